// Round 4
// baseline (302.094 us; speedup 1.0000x reference)
//
#include <hip/hip_runtime.h>
#include <hip/hip_fp16.h>
#include <stdint.h>

#define IN_F   4096
#define OUT_F  11008
#define TOKENS 2048
#define BM 256
#define BN 128
#define BK 64
#define NT (IN_F / BK)     // 64 K-tiles
#define NGROUP 32
#define OPW (OUT_F / 8)    // 1376 packed-zero words per group row

typedef _Float16 f16;
typedef __attribute__((ext_vector_type(2))) _Float16 f16x2;
typedef __attribute__((ext_vector_type(8))) _Float16 f16x8;
typedef __attribute__((ext_vector_type(4))) float f32x4;

typedef __attribute__((address_space(3))) uint32_t lds_u32_t;
typedef const __attribute__((address_space(1))) uint32_t glb_u32_t;

#define SB0() __builtin_amdgcn_sched_barrier(0)

static __device__ __forceinline__ void gload_lds16(const void* g, void* l) {
    __builtin_amdgcn_global_load_lds((glb_u32_t*)g, (lds_u32_t*)l, 16, 0, 0);
}

// dequant one packed word -> 8 f16 in pair-permuted k-order (j, j+4)
static __device__ __forceinline__ f16x8 dequant8(uint32_t w, f16x2 sv, f16x2 zv) {
    uint32_t p0 = (w & 0x000F000Fu) | 0x64006400u;           // 1024 + nibble (exact f16)
    uint32_t p1 = ((w >> 4)  & 0x000F000Fu) | 0x64006400u;
    uint32_t p2 = ((w >> 8)  & 0x000F000Fu) | 0x64006400u;
    uint32_t p3 = ((w >> 12) & 0x000F000Fu) | 0x64006400u;
    f16x2 h0 = (__builtin_bit_cast(f16x2, p0) + zv) * sv;    // exact (w - z - 1), then * s
    f16x2 h1 = (__builtin_bit_cast(f16x2, p1) + zv) * sv;
    f16x2 h2 = (__builtin_bit_cast(f16x2, p2) + zv) * sv;
    f16x2 h3 = (__builtin_bit_cast(f16x2, p3) + zv) * sv;
    f16x8 o;
    o[0] = h0[0]; o[1] = h0[1];
    o[2] = h1[0]; o[3] = h1[1];
    o[4] = h2[0]; o[5] = h2[1];
    o[6] = h3[0]; o[7] = h3[1];
    return o;
}

// pre-pass: x f32 -> f16 with intra-octet pair permutation (0,4,1,5,2,6,3,7)
__global__ __launch_bounds__(256) void cvt_perm_kernel(const float* __restrict__ x,
                                                       f16* __restrict__ xws) {
    const int o = blockIdx.x * 256 + threadIdx.x;   // octet id
    const float4 a = *reinterpret_cast<const float4*>(x + (size_t)o * 8);
    const float4 b = *reinterpret_cast<const float4*>(x + (size_t)o * 8 + 4);
    f16x8 v;
    v[0] = (f16)a.x; v[1] = (f16)b.x; v[2] = (f16)a.y; v[3] = (f16)b.y;
    v[4] = (f16)a.z; v[5] = (f16)b.z; v[6] = (f16)a.w; v[7] = (f16)b.w;
    *reinterpret_cast<f16x8*>(xws + (size_t)o * 8) = v;
}

#define MKC(SW, ZW) {                                                   \
    const float sf_ = (float)(SW) * ssv - qzssv;                        \
    const int   z_  = (int)(((ZW) >> ((ncol & 7) * 4)) & 0xFu);         \
    const f16 sh_ = (f16)sf_;                                           \
    const f16 zh_ = (f16)(float)(-(1025 + z_));                         \
    sv[0] = sh_; sv[1] = sh_; zv[0] = zh_; zv[1] = zh_;                 \
}

// Per-tile body: 2 MFMA phases (k0, k1), half-staggered A prefetch of tile T+1
// into buffer BUF^1, counted vmcnt(2) once per tile, double barrier per phase.
#define TILE_BODY(BUF, T, EVEN, WAC, WBC, WAL, WBL)                               \
  {                                                                               \
    const int tn  = ((T) + 1 < NT) ? (T) + 1 : NT - 1;                            \
    const int tn2 = ((T) + 2 < NT) ? (T) + 2 : NT - 1;                            \
    /* ---------- phase a: issue h0(t+1); wait A(t); stage B(t+1); MFMA k0 */     \
    SB0();                                                                        \
    if constexpr (USE_WS) {                                                       \
      gload_lds16(asrc[0] + (size_t)tn * BK, &Abuf[(BUF) ^ 1][aoff[0]]);          \
      gload_lds16(asrc[1] + (size_t)tn * BK, &Abuf[(BUF) ^ 1][aoff[1]]);          \
    }                                                                             \
    SB0();                                                                        \
    asm volatile("s_waitcnt vmcnt(2)" ::: "memory");  /* A(t) fully landed */     \
    __builtin_amdgcn_s_barrier();                     /* A(t) visible      */     \
    SB0();                                                                        \
    f16x8 afr[4], bfr[4];                                                         \
    _Pragma("unroll") for (int f = 0; f < 4; ++f)                                 \
      afr[f] = *reinterpret_cast<const f16x8*>(&Abuf[BUF][offA[0][f]]);           \
    _Pragma("unroll") for (int f = 0; f < 4; ++f)                                 \
      bfr[f] = *reinterpret_cast<const f16x8*>(&Bbuf[BUF][offB[0][f]]);           \
    if constexpr (!USE_WS) { stage_half_f((BUF) ^ 1, tn, 0); }                    \
    *reinterpret_cast<f16x8*>(&Bbuf[(BUF) ^ 1][bo0]) = dequant8(WAC, sv, zv);     \
    *reinterpret_cast<f16x8*>(&Bbuf[(BUF) ^ 1][bo1]) = dequant8(WBC, sv, zv);     \
    {                                                                             \
      const uint32_t* p_ = bptr + (size_t)tn2 * 8 * OUT_F;                        \
      WAL = p_[0];                                                                \
      WBL = p_[(size_t)4 * OUT_F];                                                \
    }                                                                             \
    SB0();                                                                        \
    __builtin_amdgcn_s_barrier();                                                 \
    asm volatile("s_waitcnt lgkmcnt(0)" ::: "memory");                            \
    SB0();                                                                        \
    __builtin_amdgcn_s_setprio(1);                                                \
    _Pragma("unroll") for (int i = 0; i < 4; ++i)                                 \
      _Pragma("unroll") for (int j = 0; j < 4; ++j)                               \
        acc[i][j] = __builtin_amdgcn_mfma_f32_16x16x32_f16(afr[i], bfr[j],        \
                                                           acc[i][j], 0, 0, 0);  \
    __builtin_amdgcn_s_setprio(0);                                                \
    SB0();                                                                        \
    __builtin_amdgcn_s_barrier();                                                 \
    /* ---------- phase b: issue h1(t+1); consts/group prefetch; MFMA k1 */       \
    SB0();                                                                        \
    if constexpr (USE_WS) {                                                       \
      gload_lds16(asrc[2] + (size_t)tn * BK, &Abuf[(BUF) ^ 1][aoff[2]]);          \
      gload_lds16(asrc[3] + (size_t)tn * BK, &Abuf[(BUF) ^ 1][aoff[3]]);          \
    } else { stage_half_f((BUF) ^ 1, tn, 1); }                                    \
    SB0();                                                                        \
    _Pragma("unroll") for (int f = 0; f < 4; ++f)                                 \
      afr[f] = *reinterpret_cast<const f16x8*>(&Abuf[BUF][offA[1][f]]);           \
    _Pragma("unroll") for (int f = 0; f < 4; ++f)                                 \
      bfr[f] = *reinterpret_cast<const f16x8*>(&Bbuf[BUF][offB[1][f]]);           \
    if (EVEN) {                                                                   \
      MKC(swN, zwN);                                                              \
    } else {                                                                      \
      const int gn_ = ((T) >> 1) + 2 < NGROUP ? ((T) >> 1) + 2 : NGROUP - 1;      \
      swN = qscales[(size_t)gn_ * OUT_F + ncol];                                  \
      zwN = qzeros[(size_t)gn_ * OPW + (ncol >> 3)];                              \
    }                                                                             \
    SB0();                                                                        \
    __builtin_amdgcn_s_barrier();                                                 \
    asm volatile("s_waitcnt lgkmcnt(0)" ::: "memory");                            \
    SB0();                                                                        \
    __builtin_amdgcn_s_setprio(1);                                                \
    _Pragma("unroll") for (int i = 0; i < 4; ++i)                                 \
      _Pragma("unroll") for (int j = 0; j < 4; ++j)                               \
        acc[i][j] = __builtin_amdgcn_mfma_f32_16x16x32_f16(afr[i], bfr[j],        \
                                                           acc[i][j], 0, 0, 0);  \
    __builtin_amdgcn_s_setprio(0);                                                \
    SB0();                                                                        \
    __builtin_amdgcn_s_barrier();                                                 \
  }

template<bool USE_WS>
__global__ __launch_bounds__(512, 1) void qgemm_kernel(
    const float*    __restrict__ x,
    const f16*      __restrict__ xws,
    const uint32_t* __restrict__ qweight,
    const uint32_t* __restrict__ qzeros,
    const int*      __restrict__ qscales,
    const float*    __restrict__ qscales_zeros,
    const float*    __restrict__ qscales_scales,
    float*          __restrict__ out)
{
    // chunk (row, slot) holds k-octet (slot ^ (row&7)) — conflict-free per 8-lane phase
    __shared__ __align__(16) f16 Abuf[2][BM * BK];   // 2 x 32 KiB
    __shared__ __align__(16) f16 Bbuf[2][BN * BK];   // 2 x 16 KiB

    const int tid  = threadIdx.x;
    const int lane = tid & 63;
    const int wid  = tid >> 6;      // 0..7
    const int wm   = wid >> 1;      // 0..3 (M quarter)
    const int wn   = wid & 1;       // 0..1 (N half)

    // XCD ownership: mt = blockIdx&7 -> each XCD keeps one 2MB A-panel in its L2
    const int mt = blockIdx.x & 7;
    const int nt = blockIdx.x >> 3;
    const int m0 = mt * BM;
    const int n0 = nt * BN;

    // ---------- B side: thread owns 1 column, octet rows o1 and o1+4 ----------
    const int colb = tid & 127;
    const int o1   = tid >> 7;           // 0..3
    const int ncol = n0 + colb;
    const float ssv   = qscales_scales[ncol];
    const float qzssv = qscales_zeros[ncol] * ssv;
    const int bo0 = colb * BK + ((o1    ) ^ (colb & 7)) * 8;
    const int bo1 = colb * BK + ((o1 + 4) ^ (colb & 7)) * 8;
    const uint32_t* bptr = qweight + (size_t)o1 * OUT_F + ncol;

    // ---------- A side: 4 chunks/thread (2 halves), linear dest, swizzled src ----------
    const f16*   asrc[4];
    const float* fsrc[4];
    int aoff[4];
    #pragma unroll
    for (int i = 0; i < 4; ++i) {
        const int cid = i * 512 + tid;
        const int row = cid >> 3, slot = cid & 7;
        const int oct = slot ^ (row & 7);
        asrc[i] = xws + (size_t)(m0 + row) * IN_F + oct * 8;
        fsrc[i] = x   + (size_t)(m0 + row) * IN_F + oct * 8;
        aoff[i] = cid * 8;               // f16 elems (16B chunks)
    }

    // ---------- fragment read offsets ----------
    const int lr = lane & 15;
    const int lo = lane >> 4;            // k-octet within 32-k step
    int offA[2][4], offB[2][4];
    #pragma unroll
    for (int k2 = 0; k2 < 2; ++k2)
        #pragma unroll
        for (int f = 0; f < 4; ++f) {
            const int ra = wm * 64 + f * 16 + lr;
            offA[k2][f] = ra * BK + ((k2 * 4 + lo) ^ (ra & 7)) * 8;
            const int rb = wn * 64 + f * 16 + lr;
            offB[k2][f] = rb * BK + ((k2 * 4 + lo) ^ (rb & 7)) * 8;
        }

    f32x4 acc[4][4];
    #pragma unroll
    for (int i = 0; i < 4; ++i)
        #pragma unroll
        for (int j = 0; j < 4; ++j) {
            f32x4 z = {0.f, 0.f, 0.f, 0.f};
            acc[i][j] = z;
        }

    auto stage_half_f = [&](int bufi, int tt, int h) {
        #pragma unroll
        for (int i = 2 * h; i < 2 * h + 2; ++i) {
            const float* p = fsrc[i] + (size_t)tt * BK;
            const float4 v0 = *reinterpret_cast<const float4*>(p);
            const float4 v1 = *reinterpret_cast<const float4*>(p + 4);
            f16x8 v;
            v[0] = (f16)v0.x; v[1] = (f16)v1.x; v[2] = (f16)v0.y; v[3] = (f16)v1.y;
            v[4] = (f16)v0.z; v[5] = (f16)v1.z; v[6] = (f16)v0.w; v[7] = (f16)v1.w;
            *reinterpret_cast<f16x8*>(&Abuf[bufi][aoff[i]]) = v;
        }
    };

    uint32_t wa0, wb0, wa1, wb1;
    int swN; uint32_t zwN;
    f16x2 sv, zv;

    // ---------------- prologue ----------------
    {
        // words(0) -> temps, words(1) -> pair1
        const uint32_t w0a = bptr[0];
        const uint32_t w0b = bptr[(size_t)4 * OUT_F];
        const uint32_t* p1 = bptr + (size_t)8 * OUT_F;
        wa1 = p1[0];
        wb1 = p1[(size_t)4 * OUT_F];
        const int      sw0 = qscales[ncol];
        const uint32_t zw0 = qzeros[ncol >> 3];
        // stage A tile 0 (both halves)
        if constexpr (USE_WS) {
            #pragma unroll
            for (int i = 0; i < 4; ++i)
                gload_lds16(asrc[i], &Abuf[0][aoff[i]]);
        } else {
            stage_half_f(0, 0, 0);
            stage_half_f(0, 0, 1);
        }
        MKC(sw0, zw0);                         // consts for group 0 (tiles 0,1)
        swN = qscales[OUT_F + ncol];           // group-1 prefetch
        zwN = qzeros[OPW + (ncol >> 3)];
        // stage B tile 0
        *reinterpret_cast<f16x8*>(&Bbuf[0][bo0]) = dequant8(w0a, sv, zv);
        *reinterpret_cast<f16x8*>(&Bbuf[0][bo1]) = dequant8(w0b, sv, zv);
        asm volatile("s_waitcnt vmcnt(0)" ::: "memory");
        asm volatile("s_waitcnt lgkmcnt(0)" ::: "memory");
        __builtin_amdgcn_s_barrier();
    }

    // ---------------- main loop: 2 tiles / iter ----------------
    for (int t = 0; t < NT; t += 2) {
        TILE_BODY(0, t,     true,  wa1, wb1, wa0, wb0);
        TILE_BODY(1, t + 1, false, wa0, wb0, wa1, wb1);
    }

    // ---------------- epilogue: C/D layout col=lane&15, row=(lane>>4)*4+reg ----------------
    const int orow = m0 + wm * 64 + lo * 4;
    const int ocol = n0 + wn * 64 + lr;
    #pragma unroll
    for (int i = 0; i < 4; ++i)
        #pragma unroll
        for (int j = 0; j < 4; ++j) {
            #pragma unroll
            for (int r = 0; r < 4; ++r)
                out[(size_t)(orow + i * 16 + r) * OUT_F + ocol + j * 16] = acc[i][j][r];
        }
}

extern "C" void kernel_launch(void* const* d_in, const int* in_sizes, int n_in,
                              void* d_out, int out_size, void* d_ws, size_t ws_size,
                              hipStream_t stream) {
    const float*    xp  = (const float*)d_in[0];
    const uint32_t* qw  = (const uint32_t*)d_in[1];
    const uint32_t* qz  = (const uint32_t*)d_in[2];
    const int*      qs  = (const int*)d_in[3];
    const float*    qsz = (const float*)d_in[4];
    const float*    qss = (const float*)d_in[5];
    // d_in[6] = g_idx: identity grouping (k/128), folded into the kernel.
    float* outp = (float*)d_out;

    const int grid = (TOKENS / BM) * (OUT_F / BN);   // 8 * 86 = 688
    const size_t need = (size_t)TOKENS * IN_F * sizeof(f16);   // 16 MiB

    if (ws_size >= need) {
        f16* xws = (f16*)d_ws;
        cvt_perm_kernel<<<(TOKENS * IN_F / 8) / 256, 256, 0, stream>>>(xp, xws);
        qgemm_kernel<true><<<grid, 512, 0, stream>>>(xp, xws, qw, qz, qs, qsz, qss, outp);
    } else {
        qgemm_kernel<false><<<grid, 512, 0, stream>>>(xp, (const f16*)nullptr,
                                                      qw, qz, qs, qsz, qss, outp);
    }
}

// Round 5
// 286.113 us; speedup vs baseline: 1.0559x; 1.0559x over previous
//
#include <hip/hip_runtime.h>
#include <hip/hip_fp16.h>
#include <stdint.h>

#define IN_F   4096
#define OUT_F  11008
#define TOKENS 2048
#define BM 256
#define BN 128
#define BK 64
#define NT (IN_F / BK)     // 64 K-tiles
#define NGROUP 32
#define OPW (OUT_F / 8)    // 1376 packed-zero words per group row

typedef _Float16 f16;
typedef __attribute__((ext_vector_type(2))) _Float16 f16x2;
typedef __attribute__((ext_vector_type(8))) _Float16 f16x8;
typedef __attribute__((ext_vector_type(4))) float f32x4;

typedef __attribute__((address_space(3))) uint32_t lds_u32_t;
typedef const __attribute__((address_space(1))) uint32_t glb_u32_t;

#define SB0() __builtin_amdgcn_sched_barrier(0)

static __device__ __forceinline__ void gload_lds16(const void* g, void* l) {
    __builtin_amdgcn_global_load_lds((glb_u32_t*)g, (lds_u32_t*)l, 16, 0, 0);
}

// dequant one packed word -> 8 f16 in pair-permuted k-order (j, j+4)
static __device__ __forceinline__ f16x8 dequant8(uint32_t w, f16x2 sv, f16x2 zv) {
    uint32_t p0 = (w & 0x000F000Fu) | 0x64006400u;           // 1024 + nibble (exact f16)
    uint32_t p1 = ((w >> 4)  & 0x000F000Fu) | 0x64006400u;
    uint32_t p2 = ((w >> 8)  & 0x000F000Fu) | 0x64006400u;
    uint32_t p3 = ((w >> 12) & 0x000F000Fu) | 0x64006400u;
    f16x2 h0 = (__builtin_bit_cast(f16x2, p0) + zv) * sv;    // exact (w - z - 1), then * s
    f16x2 h1 = (__builtin_bit_cast(f16x2, p1) + zv) * sv;
    f16x2 h2 = (__builtin_bit_cast(f16x2, p2) + zv) * sv;
    f16x2 h3 = (__builtin_bit_cast(f16x2, p3) + zv) * sv;
    f16x8 o;
    o[0] = h0[0]; o[1] = h0[1];
    o[2] = h1[0]; o[3] = h1[1];
    o[4] = h2[0]; o[5] = h2[1];
    o[6] = h3[0]; o[7] = h3[1];
    return o;
}

// pre-pass: x f32 -> f16 with intra-octet pair permutation (0,4,1,5,2,6,3,7)
__global__ __launch_bounds__(256) void cvt_perm_kernel(const float* __restrict__ x,
                                                       f16* __restrict__ xws) {
    const int o = blockIdx.x * 256 + threadIdx.x;   // octet id
    const float4 a = *reinterpret_cast<const float4*>(x + (size_t)o * 8);
    const float4 b = *reinterpret_cast<const float4*>(x + (size_t)o * 8 + 4);
    f16x8 v;
    v[0] = (f16)a.x; v[1] = (f16)b.x; v[2] = (f16)a.y; v[3] = (f16)b.y;
    v[4] = (f16)a.z; v[5] = (f16)b.z; v[6] = (f16)a.w; v[7] = (f16)b.w;
    *reinterpret_cast<f16x8*>(xws + (size_t)o * 8) = v;
}

#define MKC(SW, ZW) {                                                   \
    const float sf_ = (float)(SW) * ssv - qzssv;                        \
    const int   z_  = (int)(((ZW) >> ((ncol & 7) * 4)) & 0xFu);         \
    const f16 sh_ = (f16)sf_;                                           \
    const f16 zh_ = (f16)(float)(-(1025 + z_));                         \
    sv[0] = sh_; sv[1] = sh_; zv[0] = zh_; zv[1] = zh_;                 \
}

// ---- Phase 1 of tile T (buffer CUR): issue 4 A-gloads for T+1; read k-step-0
// fragments; dequant B(T+1) word0; barrier; MFMA k0; barrier.
// DO_MKC: rebuild group constants (odd tiles only), before this phase's dequant.
#define PH1(CUR, T, DO_MKC, BWC)                                                  \
  {                                                                               \
    const int tn_ = ((T) + 1 < NT) ? (T) + 1 : NT - 1;                            \
    SB0();                                                                        \
    if constexpr (USE_WS) {                                                       \
      gload_lds16(asrc[0] + (size_t)tn_ * BK, &Abuf[(CUR) ^ 1][aoff[0]]);         \
      gload_lds16(asrc[1] + (size_t)tn_ * BK, &Abuf[(CUR) ^ 1][aoff[1]]);         \
      gload_lds16(asrc[2] + (size_t)tn_ * BK, &Abuf[(CUR) ^ 1][aoff[2]]);         \
      gload_lds16(asrc[3] + (size_t)tn_ * BK, &Abuf[(CUR) ^ 1][aoff[3]]);         \
    } else {                                                                      \
      stage_A_f((CUR) ^ 1, tn_);                                                  \
    }                                                                             \
    SB0();                                                                        \
    if (DO_MKC) { MKC(swN, zwN); }                                                \
    f16x8 af[4], bf[4];                                                           \
    _Pragma("unroll") for (int f = 0; f < 4; ++f)                                 \
      af[f] = *reinterpret_cast<const f16x8*>(&Abuf[CUR][offA[0][f]]);            \
    _Pragma("unroll") for (int f = 0; f < 4; ++f)                                 \
      bf[f] = *reinterpret_cast<const f16x8*>(&Bbuf[CUR][offB[0][f]]);            \
    *reinterpret_cast<f16x8*>(&Bbuf[(CUR) ^ 1][bo0]) = dequant8((BWC), sv, zv);   \
    SB0();                                                                        \
    __builtin_amdgcn_s_barrier();                                                 \
    asm volatile("s_waitcnt lgkmcnt(0)" ::: "memory");                            \
    __builtin_amdgcn_s_setprio(1);                                                \
    _Pragma("unroll") for (int i = 0; i < 4; ++i)                                 \
      _Pragma("unroll") for (int j = 0; j < 4; ++j)                               \
        acc[i][j] = __builtin_amdgcn_mfma_f32_16x16x32_f16(af[i], bf[j],          \
                                                           acc[i][j], 0, 0, 0);  \
    __builtin_amdgcn_s_setprio(0);                                                \
    SB0();                                                                        \
    __builtin_amdgcn_s_barrier();                                                 \
  }

// ---- Phase 2 of tile T (buffer CUR): issue [sz-words, 2 B-words(T+2)]; read
// k-step-1 fragments; dequant B(T+1) word1; vmcnt(4) retires the 4 A-gloads
// issued in PH1 (leaves the 4 new loads in flight); barrier; MFMA k1; barrier.
#define PH2(CUR, T, BWC, BWL0, BWL1)                                              \
  {                                                                               \
    const int tn2_ = ((T) + 2 < NT) ? (T) + 2 : NT - 1;                           \
    const int gl_  = ((T) >> 1) + 1 < NGROUP ? ((T) >> 1) + 1 : NGROUP - 1;       \
    SB0();                                                                        \
    swN = qscales[(size_t)gl_ * OUT_F + ncol];                                    \
    zwN = qzeros[(size_t)gl_ * OPW + (ncol >> 3)];                                \
    {                                                                             \
      const uint32_t* p_ = bptr + (size_t)tn2_ * 8 * OUT_F;                       \
      BWL0 = p_[0];                                                               \
      BWL1 = p_[(size_t)4 * OUT_F];                                               \
    }                                                                             \
    SB0();                                                                        \
    f16x8 af[4], bf[4];                                                           \
    _Pragma("unroll") for (int f = 0; f < 4; ++f)                                 \
      af[f] = *reinterpret_cast<const f16x8*>(&Abuf[CUR][offA[1][f]]);            \
    _Pragma("unroll") for (int f = 0; f < 4; ++f)                                 \
      bf[f] = *reinterpret_cast<const f16x8*>(&Bbuf[CUR][offB[1][f]]);            \
    *reinterpret_cast<f16x8*>(&Bbuf[(CUR) ^ 1][bo1]) = dequant8((BWC), sv, zv);   \
    SB0();                                                                        \
    asm volatile("s_waitcnt vmcnt(4)" ::: "memory");                              \
    __builtin_amdgcn_s_barrier();                                                 \
    asm volatile("s_waitcnt lgkmcnt(0)" ::: "memory");                            \
    __builtin_amdgcn_s_setprio(1);                                                \
    _Pragma("unroll") for (int i = 0; i < 4; ++i)                                 \
      _Pragma("unroll") for (int j = 0; j < 4; ++j)                               \
        acc[i][j] = __builtin_amdgcn_mfma_f32_16x16x32_f16(af[i], bf[j],          \
                                                           acc[i][j], 0, 0, 0);  \
    __builtin_amdgcn_s_setprio(0);                                                \
    SB0();                                                                        \
    __builtin_amdgcn_s_barrier();                                                 \
  }

template<bool USE_WS>
__global__ __launch_bounds__(512, 1) void qgemm_kernel(
    const float*    __restrict__ x,
    const f16*      __restrict__ xws,
    const uint32_t* __restrict__ qweight,
    const uint32_t* __restrict__ qzeros,
    const int*      __restrict__ qscales,
    const float*    __restrict__ qscales_zeros,
    const float*    __restrict__ qscales_scales,
    float*          __restrict__ out)
{
    // chunk (row, slot) holds k-octet (slot ^ (row&7)) — conflict-free per 8-lane phase
    __shared__ __align__(16) f16 Abuf[2][BM * BK];   // 2 x 32 KiB
    __shared__ __align__(16) f16 Bbuf[2][BN * BK];   // 2 x 16 KiB

    const int tid  = threadIdx.x;
    const int lane = tid & 63;
    const int wid  = tid >> 6;      // 0..7
    const int wm   = wid >> 1;      // 0..3 (M quarter)
    const int wn   = wid & 1;       // 0..1 (N half)

    // XCD ownership: mt = blockIdx&7 -> each XCD keeps one A-panel in its L2
    const int mt = blockIdx.x & 7;
    const int nt = blockIdx.x >> 3;
    const int m0 = mt * BM;
    const int n0 = nt * BN;

    // ---------- B side: thread owns 1 column, octet rows o1 and o1+4 ----------
    const int colb = tid & 127;
    const int o1   = tid >> 7;           // 0..3
    const int ncol = n0 + colb;
    const float ssv   = qscales_scales[ncol];
    const float qzssv = qscales_zeros[ncol] * ssv;
    const int bo0 = colb * BK + ((o1    ) ^ (colb & 7)) * 8;
    const int bo1 = colb * BK + ((o1 + 4) ^ (colb & 7)) * 8;
    const uint32_t* bptr = qweight + (size_t)o1 * OUT_F + ncol;

    // ---------- A side: 4 chunks/thread, linear LDS dest, swizzled source ----------
    const f16*   asrc[4];
    const float* fsrc[4];
    int aoff[4];
    #pragma unroll
    for (int i = 0; i < 4; ++i) {
        const int cid = i * 512 + tid;
        const int row = cid >> 3, slot = cid & 7;
        const int oct = slot ^ (row & 7);
        asrc[i] = xws + (size_t)(m0 + row) * IN_F + oct * 8;
        fsrc[i] = x   + (size_t)(m0 + row) * IN_F + oct * 8;
        aoff[i] = cid * 8;               // f16 elems (16B chunks)
    }

    // ---------- fragment read offsets ----------
    const int lr = lane & 15;
    const int lo = lane >> 4;            // k-octet within 32-k step
    int offA[2][4], offB[2][4];
    #pragma unroll
    for (int k2 = 0; k2 < 2; ++k2)
        #pragma unroll
        for (int f = 0; f < 4; ++f) {
            const int ra = wm * 64 + f * 16 + lr;
            offA[k2][f] = ra * BK + ((k2 * 4 + lo) ^ (ra & 7)) * 8;
            const int rb = wn * 64 + f * 16 + lr;
            offB[k2][f] = rb * BK + ((k2 * 4 + lo) ^ (rb & 7)) * 8;
        }

    f32x4 acc[4][4];
    #pragma unroll
    for (int i = 0; i < 4; ++i)
        #pragma unroll
        for (int j = 0; j < 4; ++j) {
            f32x4 z = {0.f, 0.f, 0.f, 0.f};
            acc[i][j] = z;
        }

    auto stage_A_f = [&](int bufi, int tt) {
        #pragma unroll
        for (int i = 0; i < 4; ++i) {
            const float* p = fsrc[i] + (size_t)tt * BK;
            const float4 v0 = *reinterpret_cast<const float4*>(p);
            const float4 v1 = *reinterpret_cast<const float4*>(p + 4);
            f16x8 v;
            v[0] = (f16)v0.x; v[1] = (f16)v1.x; v[2] = (f16)v0.y; v[3] = (f16)v1.y;
            v[4] = (f16)v0.z; v[5] = (f16)v1.z; v[6] = (f16)v0.w; v[7] = (f16)v1.w;
            *reinterpret_cast<f16x8*>(&Abuf[bufi][aoff[i]]) = v;
        }
    };

    uint32_t bwE0, bwE1, bwO0, bwO1;
    int swN; uint32_t zwN;
    f16x2 sv, zv;

    // ---------------- prologue: stage tile 0, prime pair-E (B(1) words) ----------------
    {
        if constexpr (USE_WS) {
            #pragma unroll
            for (int i = 0; i < 4; ++i)
                gload_lds16(asrc[i], &Abuf[0][aoff[i]]);
        } else {
            stage_A_f(0, 0);
        }
        const uint32_t w0a = bptr[0];                      // B(0) words
        const uint32_t w0b = bptr[(size_t)4 * OUT_F];
        const uint32_t* p1 = bptr + (size_t)8 * OUT_F;     // B(1) words
        bwE0 = p1[0];
        bwE1 = p1[(size_t)4 * OUT_F];
        const int      sw0 = qscales[ncol];
        const uint32_t zw0 = qzeros[ncol >> 3];
        MKC(sw0, zw0);                                     // group 0 (tiles 0,1)
        asm volatile("s_waitcnt vmcnt(0)" ::: "memory");   // A(0) in LDS
        *reinterpret_cast<f16x8*>(&Bbuf[0][bo0]) = dequant8(w0a, sv, zv);
        *reinterpret_cast<f16x8*>(&Bbuf[0][bo1]) = dequant8(w0b, sv, zv);
        asm volatile("s_waitcnt lgkmcnt(0)" ::: "memory");
        __builtin_amdgcn_s_barrier();
    }

    // ---------------- main loop: 2 tiles (4 phases) per iteration ----------------
    for (int t = 0; t < NT; t += 2) {
        PH1(0, t,     false, bwE0);               // dequant B(t+1) word0
        PH2(0, t,     bwE1,  bwO0, bwO1);         // load B(t+2) words + sz(g+1)
        PH1(1, t + 1, true,  bwO0);               // MKC group (t+2)/2; dequant B(t+2) w0
        PH2(1, t + 1, bwO1,  bwE0, bwE1);         // load B(t+3) words + sz
    }

    // ---------------- epilogue: C/D layout col=lane&15, row=(lane>>4)*4+reg ----------------
    const int orow = m0 + wm * 64 + lo * 4;
    const int ocol = n0 + wn * 64 + lr;
    #pragma unroll
    for (int i = 0; i < 4; ++i)
        #pragma unroll
        for (int j = 0; j < 4; ++j) {
            #pragma unroll
            for (int r = 0; r < 4; ++r)
                out[(size_t)(orow + i * 16 + r) * OUT_F + ocol + j * 16] = acc[i][j][r];
        }
}

extern "C" void kernel_launch(void* const* d_in, const int* in_sizes, int n_in,
                              void* d_out, int out_size, void* d_ws, size_t ws_size,
                              hipStream_t stream) {
    const float*    xp  = (const float*)d_in[0];
    const uint32_t* qw  = (const uint32_t*)d_in[1];
    const uint32_t* qz  = (const uint32_t*)d_in[2];
    const int*      qs  = (const int*)d_in[3];
    const float*    qsz = (const float*)d_in[4];
    const float*    qss = (const float*)d_in[5];
    // d_in[6] = g_idx: identity grouping (k/128), folded into the kernel.
    float* outp = (float*)d_out;

    const int grid = (TOKENS / BM) * (OUT_F / BN);   // 8 * 86 = 688
    const size_t need = (size_t)TOKENS * IN_F * sizeof(f16);   // 16 MiB

    if (ws_size >= need) {
        f16* xws = (f16*)d_ws;
        cvt_perm_kernel<<<(TOKENS * IN_F / 8) / 256, 256, 0, stream>>>(xp, xws);
        qgemm_kernel<true><<<grid, 512, 0, stream>>>(xp, xws, qw, qz, qs, qsz, qss, outp);
    } else {
        qgemm_kernel<false><<<grid, 512, 0, stream>>>(xp, (const f16*)nullptr,
                                                      qw, qz, qs, qsz, qss, outp);
    }
}